// Round 7
// baseline (128.457 us; speedup 1.0000x reference)
//
#include <hip/hip_runtime.h>

// AMPS chain kernel v7 — row-per-lane + M-broadcast (DPP off critical path).
//
// v6 -> v7: lane (task t, batch b, row i) holds C row i AND loads only M row
// i from LDS (2 ds_read2 = 4 dwords/step — v3's LDS traffic, 4x less than
// v6). The quad then reconstructs M[k][j] = quad_perm<k>(a_j): the 16 DPP
// movs depend only on the fresh loads, NOT on C -> loop-carried path is just
// 4 independent 4-deep FMA chains (~16 cyc/step, hidden at 2+ waves/SIMD).
// v3's failure (DPP-broadcast of C inside the serial chain, ~45 cyc/step)
// and v6's failure (16 dwords/lane/step, LDS-pipe bound ~20+ us) both
// avoided.  Everything else as v6: 2 tasks/wave, flat length-sorted task
// list, identity-fill for tail mismatch, CH=8 chunks staged via
// global_load_lds w=16, NBUF=4, WAITVM(6) distance-3 pipeline, P^T stores.

#define NPOS   1024
#define SEGLEN 128
#define MAXSEG 8
#define CH     8
#define NBUF   4
#define NWAVE  2300                    // 4600 tasks / 2 per wave
#define TRI_ELEMS (523776 * 32)

template<int l>
__device__ __forceinline__ float qb(float x) {
    constexpr int ctrl = l * 0x55;     // quad_perm broadcast lane l
    return __int_as_float(__builtin_amdgcn_update_dpp(
        __float_as_int(x), __float_as_int(x), ctrl, 0xF, 0xF, false));
}
template<int ctrl>
__device__ __forceinline__ float qperm(float x) {
    return __int_as_float(__builtin_amdgcn_update_dpp(
        __float_as_int(x), __float_as_int(x), ctrl, 0xF, 0xF, false));
}

__device__ __forceinline__ void gl_lds16(const float* g, float* l) {
    __builtin_amdgcn_global_load_lds(
        (const __attribute__((address_space(1))) void*)g,
        (__attribute__((address_space(3))) void*)l, 16, 0, 0);
}

// wait until <=N vmem ops outstanding (N<=15); lgkm/exp ignored (gfx9 enc)
#define WAITVM(N) __builtin_amdgcn_s_waitcnt((N) | 0x0F70)

__device__ __forceinline__ void decode_task(int id, int& s, int& n) {
    int base = 0, cnt = 1023;
    s = 0;
    while (id >= base + cnt) { base += cnt; s++; cnt -= 128; }
    n = 1022 - (id - base);            // long chains first within each class
}

__global__ __launch_bounds__(64) void amps_seg(
        const float* __restrict__ data,   // (8, 1024)
        const float* __restrict__ tri,    // (523776, 4, 4, 2)
        float* __restrict__ segout)       // (1023, 8, 8, 4, 4) = P^T per seg
{
    const int lane = threadIdx.x;
    const int w    = blockIdx.x;          // wave id 0..2299
    const int t    = lane >> 5;           // task half 0/1
    const int q    = lane & 31;
    const int b    = q >> 2;              // batch
    const int i    = q & 3;               // C row = M row loaded

    int sA, nA, sB, nB;
    decode_task(2 * w,     sA, nA);
    decode_task(2 * w + 1, sB, nB);
    const int g0A = sA * SEGLEN,            g0B = sB * SEGLEN;
    const int stepsA = min(SEGLEN, nA + 1 - g0A);
    const int stepsB = min(SEGLEN, nB + 1 - g0B);
    const int tstA = (nA * (nA + 1) / 2 + g0A) * 32;
    const int tstB = (nB * (nB + 1) / 2 + g0B) * 32;

    const int nchA = (stepsA >> 3) + ((stepsA & 7) ? 1 : 0);
    const int nchB = (stepsB >> 3) + ((stepsB & 7) ? 1 : 0);
    const int nch  = max(nchA, nchB);     // wave-uniform loop bound

    const int g0_my    = t ? g0B : g0A;
    const int steps_my = t ? stepsB : stepsA;
    const int chunkf   = steps_my >> 3;
    const int rem      = steps_my & 7;
    const int n_my     = t ? nB : nA;
    const int s_my     = t ? sB : sA;

    __shared__ float lds[2][NBUF * CH * 32];   // 2 tasks x 4 bufs x 1KB

    // ---- per-lane 128-bit sel mask (bit=1 where data != 1.0) ----
    // lane q covers (batch q>>2, quarter q&3): 32 positions of its batch row.
    unsigned m0, m1, m2, m3;
    {
        const float4* dp4 =
            (const float4*)(data + b * NPOS + g0_my + i * 32);
        float4 f[8];
        #pragma unroll
        for (int u = 0; u < 8; u++) f[u] = dp4[u];
        unsigned piece = 0;
        #pragma unroll
        for (int u = 0; u < 8; u++) {
            piece |= (f[u].x != 1.0f) ? (1u << (u * 4 + 0)) : 0u;
            piece |= (f[u].y != 1.0f) ? (1u << (u * 4 + 1)) : 0u;
            piece |= (f[u].z != 1.0f) ? (1u << (u * 4 + 2)) : 0u;
            piece |= (f[u].w != 1.0f) ? (1u << (u * 4 + 3)) : 0u;
        }
        m0 = (unsigned)__shfl((int)piece, t * 32 + b * 4 + 0);
        m1 = (unsigned)__shfl((int)piece, t * 32 + b * 4 + 1);
        m2 = (unsigned)__shfl((int)piece, t * 32 + b * 4 + 2);
        m3 = (unsigned)__shfl((int)piece, t * 32 + b * 4 + 3);
    }

    auto stageA = [&](int c) {
        int off = min(tstA + c * 256 + lane * 4, TRI_ELEMS - 4);
        gl_lds16(tri + off, &lds[0][(c & (NBUF - 1)) * 256]);
    };
    auto stageB = [&](int c) {
        int off = min(tstB + c * 256 + lane * 4, TRI_ELEMS - 4);
        gl_lds16(tri + off, &lds[1][(c & (NBUF - 1)) * 256]);
    };

    stageA(0); stageB(0);
    stageA(1); stageB(1);
    stageA(2); stageB(2);

    float* __restrict__ mybuf = &lds[t][0];

    float c0 = (i == 0) ? 1.0f : 0.0f;    // C row i of identity
    float c1 = (i == 1) ? 1.0f : 0.0f;
    float c2 = (i == 2) ? 1.0f : 0.0f;
    float c3 = (i == 3) ? 1.0f : 0.0f;

    const float idval = ((q >> 3) == ((q >> 1) & 3)) ? 1.0f : 0.0f;

    for (int c = 0; c < nch; c++) {
        stageA(c + 3); stageB(c + 3);
        WAITVM(6);                         // chunk c staged; c+1..c+3 in flight

        // identity-fill tail slots of my task's buffer (rare path)
        if (c >= chunkf) {
            const int mstart = (c == chunkf) ? rem : 0;
            float* bp = mybuf + (c & (NBUF - 1)) * 256 + q;
            for (int m = mstart; m < CH; m++) bp[m * 32] = idval;
        }

        unsigned word = (c < 8) ? ((c < 4) ? m0 : m1) : ((c < 12) ? m2 : m3);
        const unsigned bits = (word >> ((c & 3) * 8)) & 0xFFu;
        // row base: lane reads only M row i (4 dwords, 2x ds_read2)
        const float* __restrict__ buf =
            mybuf + (c & (NBUF - 1)) * 256 + i * 8;

        #pragma unroll
        for (int m = 0; m < CH; m++) {
            const float* p = buf + m * 32 + ((bits >> m) & 1u);
            float a0 = p[0], a1 = p[2], a2 = p[4], a3 = p[6];  // M[i][0..3]
            // M[k][j] = qb<k>(a_j): DPP depends only on loads, not on C.
            // n_j = sum_k c_k * M[k][j] — 4 independent FMA chains.
            float n0 = fmaf(c3, qb<3>(a0), fmaf(c2, qb<2>(a0),
                       fmaf(c1, qb<1>(a0), c0 * qb<0>(a0))));
            float n1 = fmaf(c3, qb<3>(a1), fmaf(c2, qb<2>(a1),
                       fmaf(c1, qb<1>(a1), c0 * qb<0>(a1))));
            float n2 = fmaf(c3, qb<3>(a2), fmaf(c2, qb<2>(a2),
                       fmaf(c1, qb<1>(a2), c0 * qb<0>(a2))));
            float n3 = fmaf(c3, qb<3>(a3), fmaf(c2, qb<2>(a3),
                       fmaf(c1, qb<1>(a3), c0 * qb<0>(a3))));
            c0 = n0; c1 = n1; c2 = n2; c3 = n3;
        }
    }

    // store P^T: segout[.. + j*4 + i] = P[i][j] = c_j
    const size_t o = (((size_t)n_my * MAXSEG + s_my) * 8 + b) * 16 + i;
    segout[o +  0] = c0;
    segout[o +  4] = c1;
    segout[o +  8] = c2;
    segout[o + 12] = c3;
}

__global__ __launch_bounds__(256) void amps_combine(
        const float* __restrict__ segout, // (1023, 8, 8, 16) P^T
        const float* __restrict__ diag,   // (1024, 4, 2)
        const float* __restrict__ data,   // (8, 1024)
        float* __restrict__ out)          // (8) — pre-zeroed by memset
{
    const int tid = threadIdx.x;
    const int q   = tid >> 5;             // chain slot in block, 0..7
    const int sub = tid & 31;
    const int b   = sub >> 2;
    const int r   = sub & 3;
    const int n   = blockIdx.x * 8 + q;   // 0..1023 (1023 invalid)

    __shared__ float sh[64];

    float res = 0.0f;
    if (n < NPOS - 1) {
        const int nseg = n / SEGLEN + 1;
        const float* basep = segout + (size_t)n * (MAXSEG * 128)
                           + b * 16 + r * 4;
        float4 P[8];
        #pragma unroll
        for (int s2 = 0; s2 < 8; s2++)
            P[s2] = *(const float4*)(basep + s2 * 128);

        float v = (r == 0) ? 1.0f : 0.0f;
        #pragma unroll
        for (int s2 = 0; s2 < 8; s2++) {
            float acc = qb<0>(v) * P[s2].x;
            acc = fmaf(qb<1>(v), P[s2].y, acc);
            acc = fmaf(qb<2>(v), P[s2].z, acc);
            float vn = fmaf(qb<3>(v), P[s2].w, acc);
            v = (s2 < nseg) ? vn : v;
        }

        const int pos = n + 1;
        const float* dg = diag + pos * 8 + r * 2;
        float o0 = v * dg[0];
        float o1 = v * dg[1];
        o0 += qperm<0xB1>(o0); o0 += qperm<0x4E>(o0);   // quad sum over r
        o1 += qperm<0xB1>(o1); o1 += qperm<0x4E>(o1);
        float mx  = fmaxf(o0, o1);
        float lse = mx + __logf(__expf(o0 - mx) + __expf(o1 - mx));
        float dsel = data[b * NPOS + pos];
        res = ((dsel == 1.0f) ? o0 : o1) - lse;
    }
    if (r == 0) sh[q * 8 + b] = res;
    __syncthreads();
    if (tid < 8) {
        float ssum = 0.0f;
        #pragma unroll
        for (int qq = 0; qq < 8; qq++) ssum += sh[qq * 8 + tid];
        if (blockIdx.x == 0) {
            float o0 = diag[0], o1 = diag[1];
            float mx  = fmaxf(o0, o1);
            float lse = mx + __logf(__expf(o0 - mx) + __expf(o1 - mx));
            float d0  = data[tid * NPOS];
            ssum += ((d0 == 1.0f) ? o0 : o1) - lse;
        }
        atomicAdd(out + tid, ssum);
    }
}

extern "C" void kernel_launch(void* const* d_in, const int* in_sizes, int n_in,
                              void* d_out, int out_size, void* d_ws, size_t ws_size,
                              hipStream_t stream)
{
    const float* data = (const float*)d_in[0];   // (8, 1024)
    const float* tri  = (const float*)d_in[1];   // (523776, 4, 4, 2)
    const float* diag = (const float*)d_in[2];   // (1024, 4, 2)

    float* segout = (float*)d_ws;                // 1023*8*8*16*4 = 4,190,208 B
    float* out    = (float*)d_out;               // 8 floats

    hipMemsetAsync(d_out, 0, 8 * sizeof(float), stream);
    amps_seg<<<dim3(NWAVE), dim3(64), 0, stream>>>(data, tri, segout);
    amps_combine<<<dim3(128), dim3(256), 0, stream>>>(segout, diag, data, out);
}

// Round 8
// 121.657 us; speedup vs baseline: 1.0559x; 1.0559x over previous
//
#include <hip/hip_runtime.h>

// AMPS chain kernel v8 — DPP-folded FMA + 4x wave residency. gfx950.
//
// v7 -> v8:
// (1) Inner product written as fmac(dpp(a_j), c_k, acc): the quad_perm
//     broadcast is src0 of an accumulating VOP2 fmac, so GCNDPPCombine can
//     fold it into v_fmac_f32_dpp — removes 16 v_mov_dpp per wave-step,
//     halving inner instruction count (~10 VALU inst per task-step).
// (2) SEGLEN 128 -> 64: 8688 tasks / 4344 waves (17 waves/CU dispatched),
//     packed 4 waves per 256-thread block (32KB LDS -> 5 blocks/CU capacity,
//     fully co-resident) — raises SIMD issue utilization (v7: 41% busy at
//     ~1 wave/SIMD; target ~70% at 4+ waves/SIMD).
// (3) Branch-free main loop; identity-fill tail handling in epilogue only.
// Unchanged: 2 tasks/wave length-sorted pairing, raw-tri LDS staging via
// global_load_lds w=16 (1KB chunk/task), NBUF=4, WAITVM(6) distance-3
// pipeline, P^T segout stores, combine + block-reduce + atomicAdd.

#define NPOS   1024
#define SEGLEN 64
#define MAXSEG 16
#define CH     8
#define NBUF   4
#define NTASK  8688                    // sum_{s=0}^{15} (1023 - 64 s)
#define NWAVE  (NTASK / 2)             // 4344
#define NBLOCK (NWAVE / 4)             // 1086
#define TRI_ELEMS (523776 * 32)

template<int l>
__device__ __forceinline__ float qb(float x) {
    constexpr int ctrl = l * 0x55;     // quad_perm broadcast lane l
    return __int_as_float(__builtin_amdgcn_update_dpp(
        __float_as_int(x), __float_as_int(x), ctrl, 0xF, 0xF, false));
}
template<int ctrl>
__device__ __forceinline__ float qperm(float x) {
    return __int_as_float(__builtin_amdgcn_update_dpp(
        __float_as_int(x), __float_as_int(x), ctrl, 0xF, 0xF, false));
}

__device__ __forceinline__ void gl_lds16(const float* g, float* l) {
    __builtin_amdgcn_global_load_lds(
        (const __attribute__((address_space(1))) void*)g,
        (__attribute__((address_space(3))) void*)l, 16, 0, 0);
}

// wait until <=N vmem ops outstanding (N<=15); lgkm/exp ignored (gfx9 enc)
#define WAITVM(N) __builtin_amdgcn_s_waitcnt((N) | 0x0F70)

__device__ __forceinline__ void decode_task(int id, int& s, int& n) {
    int base = 0, cnt = 1023;
    s = 0;
    while (id >= base + cnt) { base += cnt; s++; cnt -= SEGLEN; }
    n = 1022 - (id - base);            // long chains first within each class
}

__global__ __launch_bounds__(256, 4) void amps_seg(
        const float* __restrict__ data,   // (8, 1024)
        const float* __restrict__ tri,    // (523776, 4, 4, 2)
        float* __restrict__ segout)       // (1023, 16, 8, 4, 4) = P^T per seg
{
    const int tid  = threadIdx.x;
    const int wid  = tid >> 6;
    const int lane = tid & 63;
    const int w    = blockIdx.x * 4 + wid;        // wave 0..4343
    const int t    = lane >> 5;           // task half 0/1
    const int q    = lane & 31;
    const int b    = q >> 2;              // batch
    const int i    = q & 3;               // C row = M row loaded

    int sA, nA, sB, nB;
    decode_task(2 * w,     sA, nA);
    decode_task(2 * w + 1, sB, nB);
    const int g0A = sA * SEGLEN,            g0B = sB * SEGLEN;
    const int stepsA = min(SEGLEN, nA + 1 - g0A);
    const int stepsB = min(SEGLEN, nB + 1 - g0B);
    const int tstA = (nA * (nA + 1) / 2 + g0A) * 32;
    const int tstB = (nB * (nB + 1) / 2 + g0B) * 32;

    const int fullA = stepsA >> 3,          fullB = stepsB >> 3;
    const int nchA = fullA + ((stepsA & 7) ? 1 : 0);
    const int nchB = fullB + ((stepsB & 7) ? 1 : 0);
    const int nch   = max(nchA, nchB);    // wave-uniform
    const int mainc = min(fullA, fullB);  // branch-free iterations

    const int g0_my    = t ? g0B : g0A;
    const int steps_my = t ? stepsB : stepsA;
    const int chunkf   = steps_my >> 3;
    const int rem      = steps_my & 7;
    const int n_my     = t ? nB : nA;
    const int s_my     = t ? sB : sA;

    __shared__ float lds_all[4][2][NBUF * CH * 32];   // 4 waves x 2 tasks x 4KB
    float* __restrict__ ldsA = &lds_all[wid][0][0];
    float* __restrict__ ldsB = &lds_all[wid][1][0];

    // ---- per-lane 64-bit sel mask (bit=1 where data != 1.0) ----
    // lane (t,b,i) loads 16 floats: positions [g0 + i*16, +16) of batch b.
    unsigned m0, m1;
    {
        const float4* dp4 = (const float4*)(data + b * NPOS + g0_my + i * 16);
        float4 f0 = dp4[0], f1 = dp4[1], f2 = dp4[2], f3 = dp4[3];
        unsigned piece = 0;
        piece |= (f0.x != 1.0f) ? 1u : 0;        piece |= (f0.y != 1.0f) ? 2u : 0;
        piece |= (f0.z != 1.0f) ? 4u : 0;        piece |= (f0.w != 1.0f) ? 8u : 0;
        piece |= (f1.x != 1.0f) ? 0x10u : 0;     piece |= (f1.y != 1.0f) ? 0x20u : 0;
        piece |= (f1.z != 1.0f) ? 0x40u : 0;     piece |= (f1.w != 1.0f) ? 0x80u : 0;
        piece |= (f2.x != 1.0f) ? 0x100u : 0;    piece |= (f2.y != 1.0f) ? 0x200u : 0;
        piece |= (f2.z != 1.0f) ? 0x400u : 0;    piece |= (f2.w != 1.0f) ? 0x800u : 0;
        piece |= (f3.x != 1.0f) ? 0x1000u : 0;   piece |= (f3.y != 1.0f) ? 0x2000u : 0;
        piece |= (f3.z != 1.0f) ? 0x4000u : 0;   piece |= (f3.w != 1.0f) ? 0x8000u : 0;
        const int sb = t * 32 + b * 4;
        m0 = (unsigned)__shfl((int)piece, sb + 0)
           | ((unsigned)__shfl((int)piece, sb + 1) << 16);
        m1 = (unsigned)__shfl((int)piece, sb + 2)
           | ((unsigned)__shfl((int)piece, sb + 3) << 16);
    }

    auto stageA = [&](int c) {
        int off = min(tstA + c * 256 + lane * 4, TRI_ELEMS - 4);
        gl_lds16(tri + off, ldsA + (c & (NBUF - 1)) * 256);
    };
    auto stageB = [&](int c) {
        int off = min(tstB + c * 256 + lane * 4, TRI_ELEMS - 4);
        gl_lds16(tri + off, ldsB + (c & (NBUF - 1)) * 256);
    };

    stageA(0); stageB(0);
    stageA(1); stageB(1);
    stageA(2); stageB(2);

    float* __restrict__ mybuf = t ? ldsB : ldsA;

    float c0 = (i == 0) ? 1.0f : 0.0f;    // C row i of identity
    float c1 = (i == 1) ? 1.0f : 0.0f;
    float c2 = (i == 2) ? 1.0f : 0.0f;
    float c3 = (i == 3) ? 1.0f : 0.0f;

    auto bits_of = [&](int c) -> unsigned {
        unsigned word = (c < 4) ? m0 : m1;
        return (word >> ((c & 3) * 8)) & 0xFFu;
    };

    // inner 8 steps; DPP written as src0 of mul/fmac so it folds into the op
    auto compute = [&](int c) {
        const unsigned bits = bits_of(c);
        const float* __restrict__ buf = mybuf + (c & (NBUF - 1)) * 256 + i * 8;
        #pragma unroll
        for (int m = 0; m < CH; m++) {
            const float* p = buf + m * 32 + ((bits >> m) & 1u);
            float a0 = p[0], a1 = p[2], a2 = p[4], a3 = p[6];  // M[i][0..3]
            // n_j = sum_k qb<k>(a_j) * c_k — DPP value in src0, accumulating
            float n0 = qb<0>(a0) * c0;
            n0 = fmaf(qb<1>(a0), c1, n0);
            n0 = fmaf(qb<2>(a0), c2, n0);
            n0 = fmaf(qb<3>(a0), c3, n0);
            float n1 = qb<0>(a1) * c0;
            n1 = fmaf(qb<1>(a1), c1, n1);
            n1 = fmaf(qb<2>(a1), c2, n1);
            n1 = fmaf(qb<3>(a1), c3, n1);
            float n2 = qb<0>(a2) * c0;
            n2 = fmaf(qb<1>(a2), c1, n2);
            n2 = fmaf(qb<2>(a2), c2, n2);
            n2 = fmaf(qb<3>(a2), c3, n2);
            float n3 = qb<0>(a3) * c0;
            n3 = fmaf(qb<1>(a3), c1, n3);
            n3 = fmaf(qb<2>(a3), c2, n3);
            n3 = fmaf(qb<3>(a3), c3, n3);
            c0 = n0; c1 = n1; c2 = n2; c3 = n3;
        }
    };

    // main loop: both tasks full — branch-free
    int c = 0;
    for (; c < mainc; c++) {
        stageA(c + 3); stageB(c + 3);
        WAITVM(6);
        compute(c);
    }
    // epilogue: tail chunks with identity-fill for the shorter task
    const float idval = ((q >> 3) == ((q >> 1) & 3)) ? 1.0f : 0.0f;
    for (; c < nch; c++) {
        stageA(c + 3); stageB(c + 3);
        WAITVM(6);
        if (c >= chunkf) {
            const int mstart = (c == chunkf) ? rem : 0;
            float* bp = mybuf + (c & (NBUF - 1)) * 256 + q;
            for (int m = mstart; m < CH; m++) bp[m * 32] = idval;
        }
        compute(c);
    }

    // store P^T: segout[.. + j*4 + i] = P[i][j] = c_j
    const size_t o = (((size_t)n_my * MAXSEG + s_my) * 8 + b) * 16 + i;
    segout[o +  0] = c0;
    segout[o +  4] = c1;
    segout[o +  8] = c2;
    segout[o + 12] = c3;
}

__global__ __launch_bounds__(256) void amps_combine(
        const float* __restrict__ segout, // (1023, 16, 8, 16) P^T
        const float* __restrict__ diag,   // (1024, 4, 2)
        const float* __restrict__ data,   // (8, 1024)
        float* __restrict__ out)          // (8) — pre-zeroed by memset
{
    const int tid = threadIdx.x;
    const int q   = tid >> 5;             // chain slot in block, 0..7
    const int sub = tid & 31;
    const int b   = sub >> 2;
    const int r   = sub & 3;
    const int n   = blockIdx.x * 8 + q;   // 0..1023 (1023 invalid)

    __shared__ float sh[64];

    float res = 0.0f;
    if (n < NPOS - 1) {
        const int nseg = n / SEGLEN + 1;
        const float* basep = segout + (size_t)n * (MAXSEG * 128)
                           + b * 16 + r * 4;
        float v = (r == 0) ? 1.0f : 0.0f;
        #pragma unroll
        for (int s2 = 0; s2 < MAXSEG; s2++) {
            if (s2 >= nseg) break;        // wave pairs share n -> quad-uniform
            float4 P = *(const float4*)(basep + s2 * 128);
            float acc = qb<0>(v) * P.x;
            acc = fmaf(qb<1>(v), P.y, acc);
            acc = fmaf(qb<2>(v), P.z, acc);
            v   = fmaf(qb<3>(v), P.w, acc);
        }

        const int pos = n + 1;
        const float* dg = diag + pos * 8 + r * 2;
        float o0 = v * dg[0];
        float o1 = v * dg[1];
        o0 += qperm<0xB1>(o0); o0 += qperm<0x4E>(o0);   // quad sum over r
        o1 += qperm<0xB1>(o1); o1 += qperm<0x4E>(o1);
        float mx  = fmaxf(o0, o1);
        float lse = mx + __logf(__expf(o0 - mx) + __expf(o1 - mx));
        float dsel = data[b * NPOS + pos];
        res = ((dsel == 1.0f) ? o0 : o1) - lse;
    }
    if (r == 0) sh[q * 8 + b] = res;
    __syncthreads();
    if (tid < 8) {
        float ssum = 0.0f;
        #pragma unroll
        for (int qq = 0; qq < 8; qq++) ssum += sh[qq * 8 + tid];
        if (blockIdx.x == 0) {
            float o0 = diag[0], o1 = diag[1];
            float mx  = fmaxf(o0, o1);
            float lse = mx + __logf(__expf(o0 - mx) + __expf(o1 - mx));
            float d0  = data[tid * NPOS];
            ssum += ((d0 == 1.0f) ? o0 : o1) - lse;
        }
        atomicAdd(out + tid, ssum);
    }
}

extern "C" void kernel_launch(void* const* d_in, const int* in_sizes, int n_in,
                              void* d_out, int out_size, void* d_ws, size_t ws_size,
                              hipStream_t stream)
{
    const float* data = (const float*)d_in[0];   // (8, 1024)
    const float* tri  = (const float*)d_in[1];   // (523776, 4, 4, 2)
    const float* diag = (const float*)d_in[2];   // (1024, 4, 2)

    float* segout = (float*)d_ws;                // 1023*16*8*16*4 = 8,380,416 B
    float* out    = (float*)d_out;               // 8 floats

    hipMemsetAsync(d_out, 0, 8 * sizeof(float), stream);
    amps_seg<<<dim3(NBLOCK), dim3(256), 0, stream>>>(data, tri, segout);
    amps_combine<<<dim3(128), dim3(256), 0, stream>>>(segout, diag, data, out);
}